// Round 4
// baseline (1134.494 us; speedup 1.0000x reference)
//
#include <hip/hip_runtime.h>

using bf16x8 = __attribute__((ext_vector_type(8))) short;
using f32x4  = __attribute__((ext_vector_type(4))) float;
using h2     = __attribute__((ext_vector_type(2))) _Float16;
typedef unsigned short u16;
typedef unsigned int   u32;
typedef long long      i64;

#define RB 4           // batch rows per block
#define NT 512         // threads per block
#define NBLK 2048      // 8192 / RB

#if __has_builtin(__builtin_elementwise_fma)
#define H2FMA(a, b, c) __builtin_elementwise_fma((a), (b), (c))
#else
#define H2FMA(a, b, c) ((a) * (b) + (c))
#endif

// ---- LDS layout (bytes) ---- total 74536 -> 2 blocks/CU (160KB LDS)
#define XW_OFF    0         // f16 E=exp(2*(X@W1x^T+b1)) [192][128], 16B-chunk xor-swizzled (key=row&7)
#define DC8_OFF   49152     // fp8 [16][264] rows: [0..127]=d, [128..255]=c, 8B pad (rows 4..15 zero)
#define GATES_OFF 53376     // f32 [4][520]
#define C32_OFF   61696     // f32 [4][128] master c
#define D32_OFF   63744     // f32 [4][128] master d
#define EV_OFF    65792     // f16 [4][128] exp(2v), clamped <=60000
#define BETA_OFF  66816     // f32 [192] exp(e)
#define XF_OFF    67584     // f32 [192]
#define XG_OFF    68352     // f32 [192]
#define YP_OFF    69120     // f32 [192] y_prev rows
#define W2B_OFF   69888     // f32 [128] = -2*w2
#define W2S_OFF   70400     // f32 [2] half sums of w2
#define SG_OFF    70424     // f32 [4]
#define WIH_OFF   70440     // f32 [512]
#define BIHH_OFF  72488     // f32 [512]
#define SMEM_SZ   74536

__device__ __forceinline__ u16 f2b(float f) {
  u32 u = __builtin_bit_cast(u32, f);
  u += 0x7FFFu + ((u >> 16) & 1u);
  return (u16)(u >> 16);
}
__device__ __forceinline__ u32 pk2h(float a, float b) {   // packed f16: low=a, high=b
  auto h = __builtin_amdgcn_cvt_pkrtz(a, b);              // __fp16x2 on this clang
  return __builtin_bit_cast(u32, h);
}
__device__ __forceinline__ u16 f2h(float a) { return (u16)pk2h(a, 0.f); }
__device__ __forceinline__ float fast_rcp(float x) { return __builtin_amdgcn_rcpf(x); }
__device__ __forceinline__ float sigf(float x) { return fast_rcp(1.f + __expf(-x)); }
__device__ __forceinline__ float tanh_fast(float x) { return 1.f - 2.f * fast_rcp(__expf(2.f * x) + 1.f); }
__device__ __forceinline__ u16 pk_fp8(float a, float b) {  // byte0=a, byte1=b (OCP e4m3fn on gfx950)
  return (u16)(__builtin_amdgcn_cvt_pk_fp8_f32(a, b, 0, false) & 0xFFFF);
}

// ---------------- prep: weights -> fp8/bf16 in ws ----------------
__global__ void prep_w(const float* __restrict__ w1, const float* __restrict__ whh_in,
                       u16* __restrict__ w1dc8, u16* __restrict__ w1x, u16* __restrict__ whh8) {
  int i = blockIdx.x * 256 + threadIdx.x;
  if (i < 16384) {                    // W1dc fp8 [128][256] = attn_W1[:, :256], packed pairs
    int j = i >> 7, kk = (i & 127) * 2;
    w1dc8[i] = pk_fp8(w1[j * 384 + kk], w1[j * 384 + kk + 1]);
  } else if (i < 32768) {             // W1x bf16 [128][128] = attn_W1[:, 256:384]
    int t = i - 16384; int j = t >> 7, k = t & 127;
    w1x[t] = f2b(w1[j * 384 + 256 + k]);
  } else {                            // Whh fp8 [512][128], packed pairs
    int p = i - 32768;
    whh8[p] = pk_fp8(whh_in[2 * p], whh_in[2 * p + 1]);
  }
}

// ---------------- main persistent decoder ----------------
// fp8 persistent fragments: a1 16 + ag 32 = 48 VGPRs. Measured VGPR_Count=64 at
// __launch_bounds__(512,4); LDS (74.5KB) limits us to 2 blocks/CU.
__global__ __launch_bounds__(NT, 4) void decoder_main(
    const float* __restrict__ X, const float* __restrict__ y_prev,
    const float* __restrict__ attn_b1, const float* __restrict__ attn_W2,
    const float* __restrict__ lstm_Wih, const float* __restrict__ lstm_bih, const float* __restrict__ lstm_bhh,
    const float* __restrict__ fc_W, const float* __restrict__ fc_b,
    const float* __restrict__ fcf_W, const float* __restrict__ fcf_b,
    const char* __restrict__ w1dc8, const u16* __restrict__ w1x, const char* __restrict__ whh8,
    float* __restrict__ out)
{
  extern __shared__ char smem[];
  const int tid  = threadIdx.x;
  const int lane = tid & 63;
  const int wv   = tid >> 6;     // wave 0..7
  const int nI   = lane & 15;    // MFMA n/m lane index
  const int quad = lane >> 4;    // MFMA k-group
  const int b0   = blockIdx.x * RB;

  // ---- persistent A-fragments (fp8, stay in registers across all 48 steps) ----
  // ph1: v^T = W1dc[j,k<256] @ [d|c]^T ; wave = jtile (8 frags x 2 VGPR = 16)
  i64 a1[8];
#pragma unroll
  for (int kt = 0; kt < 8; ++kt)
    a1[kt] = *(const i64*)(w1dc8 + (wv * 16 + nI) * 256 + kt * 32 + quad * 8);
  // ph5: gates^T = Whh[g,k<128] @ d^T ; wave holds gtiles wv*4..wv*4+3 (16 x 2 = 32)
  i64 ag[4][4];
#pragma unroll
  for (int gt = 0; gt < 4; ++gt)
#pragma unroll
    for (int kt = 0; kt < 4; ++kt)
      ag[gt][kt] = *(const i64*)(whh8 + ((wv * 4 + gt) * 16 + nI) * 128 + kt * 32 + quad * 8);

  // ---- LDS init ----
  {
    u32* dcw = (u32*)(smem + DC8_OFF);
    for (int i = tid; i < 1056; i += NT) dcw[i] = 0u;         // d=c=0 fp8 (rows 4..15 zero too)
    float* c32 = (float*)(smem + C32_OFF);
    c32[tid] = 0.f;
  }
  if (tid < 128) ((float*)(smem + W2B_OFF))[tid] = -2.f * attn_W2[tid];
  if (tid < 2) {
    float s = 0.f;
    for (int i = 0; i < 64; ++i) s += attn_W2[tid * 64 + i];
    ((float*)(smem + W2S_OFF))[tid] = s;
  }
  {
    ((float*)(smem + WIH_OFF))[tid]  = lstm_Wih[tid];
    ((float*)(smem + BIHH_OFF))[tid] = lstm_bih[tid] + lstm_bhh[tid];
  }
  if (tid < 192) {   // y_prev rows + XF/XG precompute (context never materialized)
    ((float*)(smem + YP_OFF))[tid] = y_prev[(size_t)b0 * 48 + tid];
    const float* xr = X + ((size_t)b0 * 48 + tid) * 128;
    float f = 0.f, g = 0.f;
#pragma unroll 8
    for (int j = 0; j < 128; j += 4) {
      float4 xv = *(const float4*)(xr + j);
      float4 wf = *(const float4*)(fc_W + j);
      float4 wg = *(const float4*)(fcf_W + 128 + j);
      f += xv.x * wf.x + xv.y * wf.y + xv.z * wf.z + xv.w * wf.w;
      g += xv.x * wg.x + xv.y * wg.y + xv.z * wg.z + xv.w * wg.w;
    }
    ((float*)(smem + XF_OFF))[tid] = f;
    ((float*)(smem + XG_OFF))[tid] = g;
  }

  // ---- startup MFMA (bf16): E = exp(2*(X@W1x^T + b1)) as f16 into LDS (wave = jtile) ----
  // clamp at 60000 (< f16 max): f16 product overflow then only happens when tanh
  // is truly saturated (inf -> rcp 0 -> tanh=1 exact); underflow to 0 -> tanh=-1 exact.
  {
    bf16x8 bx[4];
#pragma unroll
    for (int kt = 0; kt < 4; ++kt)
      bx[kt] = *(const bf16x8*)(w1x + (wv * 16 + nI) * 128 + kt * 32 + quad * 8);
    const float b1v = attn_b1[wv * 16 + nI];
    const int jcol = wv * 16 + nI;
    const int kc0  = jcol >> 3;
    const int jb   = jcol & 7;
    for (int mt = 0; mt < 12; ++mt) {
      f32x4 acc = {b1v, b1v, b1v, b1v};
#pragma unroll
      for (int kt = 0; kt < 4; ++kt) {
        const float* xp = X + ((size_t)b0 * 48 + (mt * 16 + nI)) * 128 + kt * 32 + quad * 8;
        float4 xa = *(const float4*)(xp);
        float4 xb = *(const float4*)(xp + 4);
        bf16x8 af;
        af[0] = (short)f2b(xa.x); af[1] = (short)f2b(xa.y);
        af[2] = (short)f2b(xa.z); af[3] = (short)f2b(xa.w);
        af[4] = (short)f2b(xb.x); af[5] = (short)f2b(xb.y);
        af[6] = (short)f2b(xb.z); af[7] = (short)f2b(xb.w);
        acc = __builtin_amdgcn_mfma_f32_16x16x32_bf16(af, bx[kt], acc, 0, 0, 0);
      }
#pragma unroll
      for (int i = 0; i < 4; ++i) {
        int fr = mt * 16 + quad * 4 + i;                 // flat row r*48+s ; key=(fr&7)
        u16* rowp = (u16*)(smem + XW_OFF + fr * 256);
        rowp[((kc0 ^ (fr & 7)) << 3) + jb] = f2h(fminf(__expf(2.f * acc[i]), 60000.f));
      }
    }
  }
  __syncthreads();

  const float w2s    = ((const float*)(smem + W2S_OFF))[tid & 1];
  const float fcw128 = fc_W[128];
  const float fcb    = fc_b[0];
  const int   lr     = wv >> 1;        // LSTM row this wave finishes
  const int   lj     = tid & 127;      // LSTM j within row

  for (int t = 0; t < 48; ++t) {
    // ==== S0: v-MFMA (-> EV=exp(2v) f16) and gates-MFMA; shared fp8 B-frags from DC8 ====
    {
      const char* dcrow = smem + DC8_OFF + nI * 264;
      i64 bv[8];
#pragma unroll
      for (int kt = 0; kt < 8; ++kt)
        bv[kt] = *(const i64*)(dcrow + kt * 32 + quad * 8);
      f32x4 acc = {0.f, 0.f, 0.f, 0.f};
#pragma unroll
      for (int kt = 0; kt < 8; ++kt)
        acc = __builtin_amdgcn_mfma_f32_16x16x32_fp8_fp8(a1[kt], bv[kt], acc, 0, 0, 0);
      if (nI < RB) {   // col n = r ; rows quad*4+i = j within jtile
        int j0 = wv * 16 + quad * 4;
        float e0 = fminf(__expf(2.f * acc[0]), 60000.f);
        float e1 = fminf(__expf(2.f * acc[1]), 60000.f);
        float e2 = fminf(__expf(2.f * acc[2]), 60000.f);
        float e3 = fminf(__expf(2.f * acc[3]), 60000.f);
        uint2 pv; pv.x = pk2h(e0, e1); pv.y = pk2h(e2, e3);
        *(uint2*)(smem + EV_OFF + nI * 256 + j0 * 2) = pv;
      }
#pragma unroll
      for (int gt = 0; gt < 4; ++gt) {
        f32x4 acc5 = {0.f, 0.f, 0.f, 0.f};
#pragma unroll
        for (int kt = 0; kt < 4; ++kt)     // gates K-range = d-half: reuse bv[0..3]
          acc5 = __builtin_amdgcn_mfma_f32_16x16x32_fp8_fp8(ag[gt][kt], bv[kt], acc5, 0, 0, 0);
        if (nI < RB) {
          int g0 = (wv * 4 + gt) * 16 + quad * 4;
          *(f32x4*)(smem + GATES_OFF + (nI * 520 + g0) * 4) = acc5;
        }
      }
    }
    __syncthreads();

    // ==== ph2: e[r][s] = sum_j w2_j * tanh(v+xw) ; tanh via 1-2/(E*EV+1) ====
    // f16-packed: one v_pk_fma_f16 forms E*EV+1 for a PAIR of j; then cvt+rcp+fma.
    {
      const int jh = tid & 1;
      bool act = (tid < 384);
      float e = 0.f;
      int fr = tid >> 1;
      if (act) {
        int r = fr / 48;
        const char*  xwrow = smem + XW_OFF + fr * 256 + (jh << 7);
        const char*  evrow = smem + EV_OFF + r * 256 + (jh << 7);
        const float* wnp   = (const float*)(smem + W2B_OFF) + (jh << 6);
        const int key = fr & 7;
        const h2 one2 = {(_Float16)1.f, (_Float16)1.f};
        float acc = w2s;
#pragma unroll
        for (int c0 = 0; c0 < 8; ++c0) {
          uint4  xw = *(const uint4*)(xwrow + ((c0 ^ key) << 4));
          uint4  ev = *(const uint4*)(evrow + (c0 << 4));
          float4 w0 = *(const float4*)(wnp + (c0 << 3));
          float4 w1 = *(const float4*)(wnp + (c0 << 3) + 4);
#define PH2_PAIR(xu, eu, wa, wb) { \
          h2 pq = H2FMA(__builtin_bit_cast(h2, xu), __builtin_bit_cast(h2, eu), one2); \
          acc = fmaf(wa, fast_rcp((float)pq[0]), acc); \
          acc = fmaf(wb, fast_rcp((float)pq[1]), acc); }
          PH2_PAIR(xw.x, ev.x, w0.x, w0.y)
          PH2_PAIR(xw.y, ev.y, w0.z, w0.w)
          PH2_PAIR(xw.z, ev.z, w1.x, w1.y)
          PH2_PAIR(xw.w, ev.w, w1.z, w1.w)
#undef PH2_PAIR
        }
        e = acc;
      }
      float eo = __shfl_xor(e, 1, 64);
      if (act && jh == 0) ((float*)(smem + BETA_OFF))[fr] = __expf(e + eo);
    }
    __syncthreads();

    // ==== fused: per-wave redundant row-softmax + LSTM gate finish + state update ====
    // Each wave finishes row lr = wv>>1 (64 j's). Lanes 0..47 pull the row's beta/XF/XG,
    // shfl-reduce S/F/G wave-wide -> yt stays in-register (no YT LDS round-trip, no
    // dedicated 32-thread phase, one barrier less per step).
    {
      float bb = 0.f, fb = 0.f, gb = 0.f;
      if (lane < 48) {
        float b = ((const float*)(smem + BETA_OFF))[lr * 48 + lane];
        fb = b * ((const float*)(smem + XF_OFF))[lr * 48 + lane];
        gb = b * ((const float*)(smem + XG_OFF))[lr * 48 + lane];
        bb = b;
      }
#pragma unroll
      for (int m = 1; m <= 32; m <<= 1) {
        bb += __shfl_xor(bb, m, 64); fb += __shfl_xor(fb, m, 64); gb += __shfl_xor(gb, m, 64);
      }
      float inv = fast_rcp(bb);
      float yt  = fcb + fcw128 * ((const float*)(smem + YP_OFF))[lr * 48 + t] + fb * inv;
      if ((wv & 1) == 0 && lane == 0) ((float*)(smem + SG_OFF))[lr] = gb * inv;

      const float* wih = (const float*)(smem + WIH_OFF);
      const float* bh  = (const float*)(smem + BIHH_OFF);
      const float* grow = (const float*)(smem + GATES_OFF) + lr * 520;
      float vi = grow[lj]       + yt * wih[lj]       + bh[lj];
      float vf = grow[128 + lj] + yt * wih[128 + lj] + bh[128 + lj];
      float vg = grow[256 + lj] + yt * wih[256 + lj] + bh[256 + lj];
      float vo = grow[384 + lj] + yt * wih[384 + lj] + bh[384 + lj];
      float si = sigf(vi), sf = sigf(vf), tg = tanh_fast(vg), so_ = sigf(vo);
      float* c32 = (float*)(smem + C32_OFF);
      float cn = fmaf(sf, c32[lr * 128 + lj], si * tg);
      c32[lr * 128 + lj] = cn;
      float dn = so_ * tanh_fast(cn);
      ((float*)(smem + D32_OFF))[lr * 128 + lj] = dn;
      u32 pk = (u32)__builtin_amdgcn_cvt_pk_fp8_f32(dn, cn, 0, false);  // byte0=d8, byte1=c8
      char* row8 = smem + DC8_OFF + lr * 264;
      row8[lj]       = (char)(pk & 0xFF);
      row8[128 + lj] = (char)((pk >> 8) & 0xFF);
    }
    __syncthreads();
  }

  // ==== final: y_pred = fcf_b + fcfW[:128]·d + beta·XG (waves 0..3, one row each) ====
  if (wv < RB) {
    const float* d32 = (const float*)(smem + D32_OFF) + wv * 128;
    float p = fcf_W[lane] * d32[lane] + fcf_W[lane + 64] * d32[lane + 64];
#pragma unroll
    for (int m = 1; m <= 32; m <<= 1) p += __shfl_xor(p, m, 64);
    if (lane == 0)
      out[b0 + wv] = fcf_b[0] + p + ((const float*)(smem + SG_OFF))[wv];
  }
}

// ---------------- tail: GRU over y_skip + linear skip, add into out ----------------
__global__ void tail_k(const float* __restrict__ y_skip, const float* __restrict__ y_prev,
                       const float* __restrict__ gWih, const float* __restrict__ gWhh,
                       const float* __restrict__ gbih, const float* __restrict__ gbhh,
                       const float* __restrict__ lin1W, const float* __restrict__ lin1b,
                       const float* __restrict__ lin2W, const float* __restrict__ lin2b,
                       float* __restrict__ out) {
  int b = blockIdx.x * 256 + threadIdx.x;
  if (b >= 8192) return;
  float wih[15], bi_[15], bh_[15], whh[75];
#pragma unroll
  for (int k = 0; k < 15; ++k) { wih[k] = gWih[k]; bi_[k] = gbih[k]; bh_[k] = gbhh[k]; }
#pragma unroll
  for (int k = 0; k < 75; ++k) whh[k] = gWhh[k];
  float h[5] = {0.f, 0.f, 0.f, 0.f, 0.f};
  for (int l = 0; l < 24; ++l) {
    float x = y_skip[(size_t)b * 24 + l];
    float nh[5];
#pragma unroll
    for (int i = 0; i < 5; ++i) {
      float ghr = bh_[i], ghz = bh_[5 + i], ghn = bh_[10 + i];
#pragma unroll
      for (int q = 0; q < 5; ++q) {
        ghr = fmaf(whh[i * 5 + q], h[q], ghr);
        ghz = fmaf(whh[(5 + i) * 5 + q], h[q], ghz);
        ghn = fmaf(whh[(10 + i) * 5 + q], h[q], ghn);
      }
      float rr = sigf(fmaf(wih[i], x, bi_[i]) + ghr);
      float zz = sigf(fmaf(wih[5 + i], x, bi_[5 + i]) + ghz);
      float nn = tanh_fast(fmaf(wih[10 + i], x, bi_[10 + i]) + rr * ghn);
      nh[i] = (1.f - zz) * nn + zz * h[i];
    }
#pragma unroll
    for (int i = 0; i < 5; ++i) h[i] = nh[i];
  }
  float ss = lin1b[0];
#pragma unroll
  for (int i = 0; i < 5; ++i) ss = fmaf(lin1W[i], h[i], ss);
  float sl = lin2b[0];
  const float* ypr = y_prev + (size_t)b * 48;
#pragma unroll 12
  for (int s = 0; s < 48; ++s) sl = fmaf(lin2W[s], ypr[s], sl);
  out[b] = out[b] + ss + sl;
}

extern "C" void kernel_launch(void* const* d_in, const int* in_sizes, int n_in,
                              void* d_out, int out_size, void* d_ws, size_t ws_size,
                              hipStream_t stream) {
  (void)in_sizes; (void)n_in; (void)out_size; (void)ws_size;
  const float* X        = (const float*)d_in[0];
  const float* y_prev   = (const float*)d_in[1];
  const float* y_skip   = (const float*)d_in[2];
  const float* attn_W1  = (const float*)d_in[3];
  const float* attn_b1  = (const float*)d_in[4];
  const float* attn_W2  = (const float*)d_in[5];
  /* d_in[6] attn_b2: softmax shift-invariant, unused */
  const float* lstm_Wih = (const float*)d_in[7];
  const float* lstm_bih = (const float*)d_in[9];
  const float* lstm_Whh = (const float*)d_in[8];
  const float* lstm_bhh = (const float*)d_in[10];
  const float* fc_W     = (const float*)d_in[11];
  const float* fc_b     = (const float*)d_in[12];
  const float* fcf_W    = (const float*)d_in[13];
  const float* fcf_b    = (const float*)d_in[14];
  const float* gWih     = (const float*)d_in[15];
  const float* gWhh     = (const float*)d_in[16];
  const float* gbih     = (const float*)d_in[17];
  const float* gbhh     = (const float*)d_in[18];
  const float* lin1W    = (const float*)d_in[19];
  const float* lin1b    = (const float*)d_in[20];
  const float* lin2W    = (const float*)d_in[21];
  const float* lin2b    = (const float*)d_in[22];
  float* out = (float*)d_out;

  char* w1dc8 = (char*)d_ws;                      // fp8 [128][256], 32768 B
  char* whh8  = (char*)d_ws + 32768;              // fp8 [512][128], 65536 B
  u16*  w1x   = (u16*)((char*)d_ws + 98304);      // bf16 [128][128], 32768 B

  prep_w<<<256, 256, 0, stream>>>(attn_W1, lstm_Whh, (u16*)w1dc8, w1x, (u16*)whh8);
  decoder_main<<<NBLK, NT, SMEM_SZ, stream>>>(X, y_prev, attn_b1, attn_W2,
                                              lstm_Wih, lstm_bih, lstm_bhh,
                                              fc_W, fc_b, fcf_W, fcf_b,
                                              w1dc8, w1x, whh8, out);
  tail_k<<<32, 256, 0, stream>>>(y_skip, y_prev, gWih, gWhh, gbih, gbhh,
                                 lin1W, lin1b, lin2W, lin2b, out);
}

// Round 5
// 989.268 us; speedup vs baseline: 1.1468x; 1.1468x over previous
//
#include <hip/hip_runtime.h>

using bf16x8 = __attribute__((ext_vector_type(8))) short;
using f32x4  = __attribute__((ext_vector_type(4))) float;
using h2     = __attribute__((ext_vector_type(2))) _Float16;
typedef unsigned short u16;
typedef unsigned int   u32;
typedef long long      i64;

#define RB 4           // batch rows per block
#define NT 512         // threads per block
#define NBLK 2048      // 8192 / RB

#if __has_builtin(__builtin_elementwise_fma)
#define H2FMA(a, b, c) __builtin_elementwise_fma((a), (b), (c))
#else
#define H2FMA(a, b, c) ((a) * (b) + (c))
#endif

// f16 reciprocal; (float)rcph(h) feeds v_fma_mix_f32 (mad-mix pattern) so the
// per-element chain is rcp_f16 + fma_mix = 2 instrs vs cvt + rcp_f32 + fma = 3.
#if __has_builtin(__builtin_amdgcn_rcph)
#define RCPH(x) ((float)__builtin_amdgcn_rcph(x))
#else
#define RCPH(x) __builtin_amdgcn_rcpf((float)(x))
#endif

// ---- LDS layout (bytes) ---- total 74536 -> 2 blocks/CU (160KB LDS)
#define XW_OFF    0         // f16 E=exp(2*(X@W1x^T+b1)) [192][128], 16B-chunk xor-swizzled (key=row&7)
#define DC8_OFF   49152     // fp8 [16][264] rows: [0..127]=d, [128..255]=c, 8B pad (rows 4..15 zero)
#define GATES_OFF 53376     // f32 [4][520]
#define C32_OFF   61696     // f32 [4][128] master c
#define D32_OFF   63744     // f32 [4][128] master d
#define EV_OFF    65792     // f16 [4][128] exp(2v), clamped <=60000
#define BETA_OFF  66816     // f32 [192] exp(e)
#define XF_OFF    67584     // f32 [192]
#define XG_OFF    68352     // f32 [192]
#define YP_OFF    69120     // f32 [192] y_prev rows
#define W2B_OFF   69888     // f32 [128] = -2*w2
#define W2S_OFF   70400     // f32 [2] half sums of w2
#define YT_OFF    70408     // f32 [4]
#define SG_OFF    70424     // f32 [4]
#define WIH_OFF   70440     // f32 [512]
#define BIHH_OFF  72488     // f32 [512]
#define SMEM_SZ   74536

__device__ __forceinline__ u16 f2b(float f) {
  u32 u = __builtin_bit_cast(u32, f);
  u += 0x7FFFu + ((u >> 16) & 1u);
  return (u16)(u >> 16);
}
__device__ __forceinline__ u32 pk2h(float a, float b) {   // packed f16: low=a, high=b
  auto h = __builtin_amdgcn_cvt_pkrtz(a, b);              // __fp16x2 on this clang
  return __builtin_bit_cast(u32, h);
}
__device__ __forceinline__ u16 f2h(float a) { return (u16)pk2h(a, 0.f); }
__device__ __forceinline__ float fast_rcp(float x) { return __builtin_amdgcn_rcpf(x); }
__device__ __forceinline__ float sigf(float x) { return fast_rcp(1.f + __expf(-x)); }
__device__ __forceinline__ float tanh_fast(float x) { return 1.f - 2.f * fast_rcp(__expf(2.f * x) + 1.f); }
__device__ __forceinline__ u16 pk_fp8(float a, float b) {  // byte0=a, byte1=b (OCP e4m3fn on gfx950)
  return (u16)(__builtin_amdgcn_cvt_pk_fp8_f32(a, b, 0, false) & 0xFFFF);
}

// ---------------- prep: weights -> fp8/bf16 in ws ----------------
__global__ void prep_w(const float* __restrict__ w1, const float* __restrict__ whh_in,
                       u16* __restrict__ w1dc8, u16* __restrict__ w1x, u16* __restrict__ whh8) {
  int i = blockIdx.x * 256 + threadIdx.x;
  if (i < 16384) {                    // W1dc fp8 [128][256] = attn_W1[:, :256], packed pairs
    int j = i >> 7, kk = (i & 127) * 2;
    w1dc8[i] = pk_fp8(w1[j * 384 + kk], w1[j * 384 + kk + 1]);
  } else if (i < 32768) {             // W1x bf16 [128][128] = attn_W1[:, 256:384]
    int t = i - 16384; int j = t >> 7, k = t & 127;
    w1x[t] = f2b(w1[j * 384 + 256 + k]);
  } else {                            // Whh fp8 [512][128], packed pairs
    int p = i - 32768;
    whh8[p] = pk_fp8(whh_in[2 * p], whh_in[2 * p + 1]);
  }
}

// ---------------- main persistent decoder ----------------
// fp8 persistent fragments: a1 16 + ag 32 = 48 VGPRs. Measured VGPR_Count=64 at
// __launch_bounds__(512,4); LDS (74.5KB) limits us to 2 blocks/CU.
__global__ __launch_bounds__(NT, 4) void decoder_main(
    const float* __restrict__ X, const float* __restrict__ y_prev,
    const float* __restrict__ attn_b1, const float* __restrict__ attn_W2,
    const float* __restrict__ lstm_Wih, const float* __restrict__ lstm_bih, const float* __restrict__ lstm_bhh,
    const float* __restrict__ fc_W, const float* __restrict__ fc_b,
    const float* __restrict__ fcf_W, const float* __restrict__ fcf_b,
    const char* __restrict__ w1dc8, const u16* __restrict__ w1x, const char* __restrict__ whh8,
    float* __restrict__ out)
{
  extern __shared__ char smem[];
  const int tid  = threadIdx.x;
  const int lane = tid & 63;
  const int wv   = tid >> 6;     // wave 0..7
  const int nI   = lane & 15;    // MFMA n/m lane index
  const int quad = lane >> 4;    // MFMA k-group
  const int b0   = blockIdx.x * RB;

  // ---- persistent A-fragments (fp8, stay in registers across all 48 steps) ----
  // ph1: v^T = W1dc[j,k<256] @ [d|c]^T ; wave = jtile (8 frags x 2 VGPR = 16)
  i64 a1[8];
#pragma unroll
  for (int kt = 0; kt < 8; ++kt)
    a1[kt] = *(const i64*)(w1dc8 + (wv * 16 + nI) * 256 + kt * 32 + quad * 8);
  // ph5: gates^T = Whh[g,k<128] @ d^T ; wave holds gtiles wv*4..wv*4+3 (16 x 2 = 32)
  i64 ag[4][4];
#pragma unroll
  for (int gt = 0; gt < 4; ++gt)
#pragma unroll
    for (int kt = 0; kt < 4; ++kt)
      ag[gt][kt] = *(const i64*)(whh8 + ((wv * 4 + gt) * 16 + nI) * 128 + kt * 32 + quad * 8);

  // ---- LDS init ----
  {
    u32* dcw = (u32*)(smem + DC8_OFF);
    for (int i = tid; i < 1056; i += NT) dcw[i] = 0u;         // d=c=0 fp8 (rows 4..15 zero too)
    float* c32 = (float*)(smem + C32_OFF);
    c32[tid] = 0.f;
  }
  if (tid < 128) ((float*)(smem + W2B_OFF))[tid] = -2.f * attn_W2[tid];
  if (tid < 2) {
    float s = 0.f;
    for (int i = 0; i < 64; ++i) s += attn_W2[tid * 64 + i];
    ((float*)(smem + W2S_OFF))[tid] = s;
  }
  {
    ((float*)(smem + WIH_OFF))[tid]  = lstm_Wih[tid];
    ((float*)(smem + BIHH_OFF))[tid] = lstm_bih[tid] + lstm_bhh[tid];
  }
  if (tid < 192) {   // y_prev rows + XF/XG precompute (context never materialized)
    ((float*)(smem + YP_OFF))[tid] = y_prev[(size_t)b0 * 48 + tid];
    const float* xr = X + ((size_t)b0 * 48 + tid) * 128;
    float f = 0.f, g = 0.f;
#pragma unroll 8
    for (int j = 0; j < 128; j += 4) {
      float4 xv = *(const float4*)(xr + j);
      float4 wf = *(const float4*)(fc_W + j);
      float4 wg = *(const float4*)(fcf_W + 128 + j);
      f += xv.x * wf.x + xv.y * wf.y + xv.z * wf.z + xv.w * wf.w;
      g += xv.x * wg.x + xv.y * wg.y + xv.z * wg.z + xv.w * wg.w;
    }
    ((float*)(smem + XF_OFF))[tid] = f;
    ((float*)(smem + XG_OFF))[tid] = g;
  }

  // ---- startup MFMA (bf16): E = exp(2*(X@W1x^T + b1)) as f16 into LDS (wave = jtile) ----
  // clamp at 60000 (< f16 max): f16 product overflow then only happens when tanh
  // is truly saturated (inf -> rcp 0 -> tanh=1 exact); underflow to 0 -> tanh=-1 exact.
  {
    bf16x8 bx[4];
#pragma unroll
    for (int kt = 0; kt < 4; ++kt)
      bx[kt] = *(const bf16x8*)(w1x + (wv * 16 + nI) * 128 + kt * 32 + quad * 8);
    const float b1v = attn_b1[wv * 16 + nI];
    const int jcol = wv * 16 + nI;
    const int kc0  = jcol >> 3;
    const int jb   = jcol & 7;
    for (int mt = 0; mt < 12; ++mt) {
      f32x4 acc = {b1v, b1v, b1v, b1v};
#pragma unroll
      for (int kt = 0; kt < 4; ++kt) {
        const float* xp = X + ((size_t)b0 * 48 + (mt * 16 + nI)) * 128 + kt * 32 + quad * 8;
        float4 xa = *(const float4*)(xp);
        float4 xb = *(const float4*)(xp + 4);
        bf16x8 af;
        af[0] = (short)f2b(xa.x); af[1] = (short)f2b(xa.y);
        af[2] = (short)f2b(xa.z); af[3] = (short)f2b(xa.w);
        af[4] = (short)f2b(xb.x); af[5] = (short)f2b(xb.y);
        af[6] = (short)f2b(xb.z); af[7] = (short)f2b(xb.w);
        acc = __builtin_amdgcn_mfma_f32_16x16x32_bf16(af, bx[kt], acc, 0, 0, 0);
      }
#pragma unroll
      for (int i = 0; i < 4; ++i) {
        int fr = mt * 16 + quad * 4 + i;                 // flat row r*48+s ; key=(fr&7)
        u16* rowp = (u16*)(smem + XW_OFF + fr * 256);
        rowp[((kc0 ^ (fr & 7)) << 3) + jb] = f2h(fminf(__expf(2.f * acc[i]), 60000.f));
      }
    }
  }
  __syncthreads();

  const float w2s    = ((const float*)(smem + W2S_OFF))[tid & 1];
  const float fcw128 = fc_W[128];
  const float fcb    = fc_b[0];

  for (int t = 0; t < 48; ++t) {
    // ==== S0: v-MFMA (-> EV=exp(2v) f16) and gates-MFMA; shared fp8 B-frags from DC8 ====
    {
      const char* dcrow = smem + DC8_OFF + nI * 264;
      i64 bv[8];
#pragma unroll
      for (int kt = 0; kt < 8; ++kt)
        bv[kt] = *(const i64*)(dcrow + kt * 32 + quad * 8);
      f32x4 acc = {0.f, 0.f, 0.f, 0.f};
#pragma unroll
      for (int kt = 0; kt < 8; ++kt)
        acc = __builtin_amdgcn_mfma_f32_16x16x32_fp8_fp8(a1[kt], bv[kt], acc, 0, 0, 0);
      if (nI < RB) {   // col n = r ; rows quad*4+i = j within jtile
        int j0 = wv * 16 + quad * 4;
        float e0 = fminf(__expf(2.f * acc[0]), 60000.f);
        float e1 = fminf(__expf(2.f * acc[1]), 60000.f);
        float e2 = fminf(__expf(2.f * acc[2]), 60000.f);
        float e3 = fminf(__expf(2.f * acc[3]), 60000.f);
        uint2 pv; pv.x = pk2h(e0, e1); pv.y = pk2h(e2, e3);
        *(uint2*)(smem + EV_OFF + nI * 256 + j0 * 2) = pv;
      }
#pragma unroll
      for (int gt = 0; gt < 4; ++gt) {
        f32x4 acc5 = {0.f, 0.f, 0.f, 0.f};
#pragma unroll
        for (int kt = 0; kt < 4; ++kt)     // gates K-range = d-half: reuse bv[0..3]
          acc5 = __builtin_amdgcn_mfma_f32_16x16x32_fp8_fp8(ag[gt][kt], bv[kt], acc5, 0, 0, 0);
        if (nI < RB) {
          int g0 = (wv * 4 + gt) * 16 + quad * 4;
          *(f32x4*)(smem + GATES_OFF + (nI * 520 + g0) * 4) = acc5;
        }
      }
    }
    __syncthreads();

    // ==== ph2: e[r][s] = sum_j w2_j * tanh(v+xw) ; tanh via 1-2/(E*EV+1) ====
    // Per pair: pk_fma (E*EV+1) -> 2x v_rcp_f16 -> 2x v_fma_mix_f32 (f16 src folded).
    {
      const int jh = tid & 1;
      bool act = (tid < 384);
      float e = 0.f;
      int fr = tid >> 1;
      if (act) {
        int r = fr / 48;
        const char*  xwrow = smem + XW_OFF + fr * 256 + (jh << 7);
        const char*  evrow = smem + EV_OFF + r * 256 + (jh << 7);
        const float* wnp   = (const float*)(smem + W2B_OFF) + (jh << 6);
        const int key = fr & 7;
        const h2 one2 = {(_Float16)1.f, (_Float16)1.f};
        float acc = w2s;
#pragma unroll
        for (int c0 = 0; c0 < 8; ++c0) {
          uint4  xw = *(const uint4*)(xwrow + ((c0 ^ key) << 4));
          uint4  ev = *(const uint4*)(evrow + (c0 << 4));
          float4 w0 = *(const float4*)(wnp + (c0 << 3));
          float4 w1 = *(const float4*)(wnp + (c0 << 3) + 4);
#define PH2_PAIR(xu, eu, wa, wb) { \
          h2 pq = H2FMA(__builtin_bit_cast(h2, xu), __builtin_bit_cast(h2, eu), one2); \
          acc = fmaf(wa, RCPH(pq[0]), acc); \
          acc = fmaf(wb, RCPH(pq[1]), acc); }
          PH2_PAIR(xw.x, ev.x, w0.x, w0.y)
          PH2_PAIR(xw.y, ev.y, w0.z, w0.w)
          PH2_PAIR(xw.z, ev.z, w1.x, w1.y)
          PH2_PAIR(xw.w, ev.w, w1.z, w1.w)
#undef PH2_PAIR
        }
        e = acc;
      }
      float eo = __shfl_xor(e, 1, 64);
      if (act && jh == 0) ((float*)(smem + BETA_OFF))[fr] = __expf(e + eo);
    }
    __syncthreads();

    // ==== softmax + y_tilde + final-context dot (first 32 lanes) ====
    if (tid < 32) {
      int r = tid >> 3, so = tid & 7;
      const float* bp = (const float*)(smem + BETA_OFF) + r * 48 + so * 6;
      const float* fp = (const float*)(smem + XF_OFF) + r * 48 + so * 6;
      const float* gp = (const float*)(smem + XG_OFF) + r * 48 + so * 6;
      float S = 0.f, F = 0.f, G = 0.f;
#pragma unroll
      for (int i = 0; i < 6; ++i) { float b = bp[i]; S += b; F = fmaf(b, fp[i], F); G = fmaf(b, gp[i], G); }
#pragma unroll
      for (int m = 1; m <= 4; m <<= 1) {
        S += __shfl_xor(S, m, 64); F += __shfl_xor(F, m, 64); G += __shfl_xor(G, m, 64);
      }
      if (so == 0) {
        float inv = 1.0f / S;
        ((float*)(smem + YT_OFF))[r] = fcb + fcw128 * ((const float*)(smem + YP_OFF))[r * 48 + t] + F * inv;
        ((float*)(smem + SG_OFF))[r] = G * inv;
      }
    }
    __syncthreads();

    // ==== LSTM gate finish + state update (512 threads = 4 rows x 128 j exactly) ====
    {
      const float* wih = (const float*)(smem + WIH_OFF);
      const float* bh  = (const float*)(smem + BIHH_OFF);
      int r = tid >> 7, j = tid & 127;
      const float* grow = (const float*)(smem + GATES_OFF) + r * 520;
      float yt = ((const float*)(smem + YT_OFF))[r];
      float vi = grow[j]       + yt * wih[j]       + bh[j];
      float vf = grow[128 + j] + yt * wih[128 + j] + bh[128 + j];
      float vg = grow[256 + j] + yt * wih[256 + j] + bh[256 + j];
      float vo = grow[384 + j] + yt * wih[384 + j] + bh[384 + j];
      float si = sigf(vi), sf = sigf(vf), tg = tanh_fast(vg), so_ = sigf(vo);
      float* c32 = (float*)(smem + C32_OFF);
      float cn = fmaf(sf, c32[r * 128 + j], si * tg);
      c32[r * 128 + j] = cn;
      float dn = so_ * tanh_fast(cn);
      ((float*)(smem + D32_OFF))[r * 128 + j] = dn;
      u32 pk = (u32)__builtin_amdgcn_cvt_pk_fp8_f32(dn, cn, 0, false);  // byte0=d8, byte1=c8
      char* row8 = smem + DC8_OFF + r * 264;
      row8[j]       = (char)(pk & 0xFF);
      row8[128 + j] = (char)((pk >> 8) & 0xFF);
    }
    __syncthreads();
  }

  // ==== final: y_pred = fcf_b + fcfW[:128]·d + beta·XG (waves 0..3, one row each) ====
  if (wv < RB) {
    const float* d32 = (const float*)(smem + D32_OFF) + wv * 128;
    float p = fcf_W[lane] * d32[lane] + fcf_W[lane + 64] * d32[lane + 64];
#pragma unroll
    for (int m = 1; m <= 32; m <<= 1) p += __shfl_xor(p, m, 64);
    if (lane == 0)
      out[b0 + wv] = fcf_b[0] + p + ((const float*)(smem + SG_OFF))[wv];
  }
}

// ---------------- tail: GRU over y_skip + linear skip, add into out ----------------
__global__ void tail_k(const float* __restrict__ y_skip, const float* __restrict__ y_prev,
                       const float* __restrict__ gWih, const float* __restrict__ gWhh,
                       const float* __restrict__ gbih, const float* __restrict__ gbhh,
                       const float* __restrict__ lin1W, const float* __restrict__ lin1b,
                       const float* __restrict__ lin2W, const float* __restrict__ lin2b,
                       float* __restrict__ out) {
  int b = blockIdx.x * 256 + threadIdx.x;
  if (b >= 8192) return;
  float wih[15], bi_[15], bh_[15], whh[75];
#pragma unroll
  for (int k = 0; k < 15; ++k) { wih[k] = gWih[k]; bi_[k] = gbih[k]; bh_[k] = gbhh[k]; }
#pragma unroll
  for (int k = 0; k < 75; ++k) whh[k] = gWhh[k];
  float h[5] = {0.f, 0.f, 0.f, 0.f, 0.f};
  for (int l = 0; l < 24; ++l) {
    float x = y_skip[(size_t)b * 24 + l];
    float nh[5];
#pragma unroll
    for (int i = 0; i < 5; ++i) {
      float ghr = bh_[i], ghz = bh_[5 + i], ghn = bh_[10 + i];
#pragma unroll
      for (int q = 0; q < 5; ++q) {
        ghr = fmaf(whh[i * 5 + q], h[q], ghr);
        ghz = fmaf(whh[(5 + i) * 5 + q], h[q], ghz);
        ghn = fmaf(whh[(10 + i) * 5 + q], h[q], ghn);
      }
      float rr = sigf(fmaf(wih[i], x, bi_[i]) + ghr);
      float zz = sigf(fmaf(wih[5 + i], x, bi_[5 + i]) + ghz);
      float nn = tanh_fast(fmaf(wih[10 + i], x, bi_[10 + i]) + rr * ghn);
      nh[i] = (1.f - zz) * nn + zz * h[i];
    }
#pragma unroll
    for (int i = 0; i < 5; ++i) h[i] = nh[i];
  }
  float ss = lin1b[0];
#pragma unroll
  for (int i = 0; i < 5; ++i) ss = fmaf(lin1W[i], h[i], ss);
  float sl = lin2b[0];
  const float* ypr = y_prev + (size_t)b * 48;
#pragma unroll 12
  for (int s = 0; s < 48; ++s) sl = fmaf(lin2W[s], ypr[s], sl);
  out[b] = out[b] + ss + sl;
}

extern "C" void kernel_launch(void* const* d_in, const int* in_sizes, int n_in,
                              void* d_out, int out_size, void* d_ws, size_t ws_size,
                              hipStream_t stream) {
  (void)in_sizes; (void)n_in; (void)out_size; (void)ws_size;
  const float* X        = (const float*)d_in[0];
  const float* y_prev   = (const float*)d_in[1];
  const float* y_skip   = (const float*)d_in[2];
  const float* attn_W1  = (const float*)d_in[3];
  const float* attn_b1  = (const float*)d_in[4];
  const float* attn_W2  = (const float*)d_in[5];
  /* d_in[6] attn_b2: softmax shift-invariant, unused */
  const float* lstm_Wih = (const float*)d_in[7];
  const float* lstm_Whh = (const float*)d_in[8];
  const float* lstm_bih = (const float*)d_in[9];
  const float* lstm_bhh = (const float*)d_in[10];
  const float* fc_W     = (const float*)d_in[11];
  const float* fc_b     = (const float*)d_in[12];
  const float* fcf_W    = (const float*)d_in[13];
  const float* fcf_b    = (const float*)d_in[14];
  const float* gWih     = (const float*)d_in[15];
  const float* gWhh     = (const float*)d_in[16];
  const float* gbih     = (const float*)d_in[17];
  const float* gbhh     = (const float*)d_in[18];
  const float* lin1W    = (const float*)d_in[19];
  const float* lin1b    = (const float*)d_in[20];
  const float* lin2W    = (const float*)d_in[21];
  const float* lin2b    = (const float*)d_in[22];
  float* out = (float*)d_out;

  char* w1dc8 = (char*)d_ws;                      // fp8 [128][256], 32768 B
  char* whh8  = (char*)d_ws + 32768;              // fp8 [512][128], 65536 B
  u16*  w1x   = (u16*)((char*)d_ws + 98304);      // bf16 [128][128], 32768 B

  prep_w<<<256, 256, 0, stream>>>(attn_W1, lstm_Whh, (u16*)w1dc8, w1x, (u16*)whh8);
  decoder_main<<<NBLK, NT, SMEM_SZ, stream>>>(X, y_prev, attn_b1, attn_W2,
                                              lstm_Wih, lstm_bih, lstm_bhh,
                                              fc_W, fc_b, fcf_W, fcf_b,
                                              w1dc8, w1x, whh8, out);
  tail_k<<<32, 256, 0, stream>>>(y_skip, y_prev, gWih, gWhh, gbih, gbhh,
                                 lin1W, lin1b, lin2W, lin2b, out);
}